// Round 3
// baseline (846.267 us; speedup 1.0000x reference)
//
#include <hip/hip_runtime.h>

#define BB 4
#define CC 512
#define C8 64
#define NN 4096
#define EPSI 1e-5f

// ---------------------------------------------------------------------------
// Projections: out[b][r][n] = sum_k w[r][k] * x[b][k][n] + bias[r]
// Tile: all 64 rows x 64 cols, K-chunks of 64. Weight tiles stored transposed
// (wT[k][r]) so the inner loop reads them as float4 broadcasts.
// NOTE: weight tile second dim is 64 output rows + 4 pad = 68 (NOT 36 —
// that was an out-of-bounds race in round 1).
// ---------------------------------------------------------------------------
__global__ __launch_bounds__(256) void proj2_kernel(
    const float* __restrict__ x1,
    const float* __restrict__ tw, const float* __restrict__ tb,
    const float* __restrict__ pw, const float* __restrict__ pb,
    float* __restrict__ theta, float* __restrict__ phi) {
  __shared__ float xs[64][64];
  __shared__ float wtT[64][68];
  __shared__ float wpT[64][68];
  const int b = blockIdx.y;
  const int n0 = blockIdx.x * 64;
  const int t = threadIdx.x;
  const int col = t & 63;
  const int q4 = t >> 6;            // 0..3
  const int rbase = q4 * 16;
  const float* xb = x1 + (size_t)b * CC * NN;
  float at[16], ap[16];
#pragma unroll
  for (int i = 0; i < 16; ++i) { at[i] = 0.f; ap[i] = 0.f; }
  for (int k0 = 0; k0 < CC; k0 += 64) {
    __syncthreads();
#pragma unroll
    for (int j = 0; j < 16; ++j) {
      int kk = q4 + j * 4;   // k-within-chunk for xs, output-row for wT
      xs[kk][col] = xb[(size_t)(k0 + kk) * NN + n0 + col];
      wtT[col][kk] = tw[kk * CC + k0 + col];
      wpT[col][kk] = pw[kk * CC + k0 + col];
    }
    __syncthreads();
#pragma unroll 4
    for (int kk = 0; kk < 64; ++kk) {
      float xv = xs[kk][col];
      const float4* qt = (const float4*)&wtT[kk][rbase];
      const float4* qp = (const float4*)&wpT[kk][rbase];
#pragma unroll
      for (int i4 = 0; i4 < 4; ++i4) {
        float4 tv = qt[i4];
        float4 pv = qp[i4];
        at[i4 * 4 + 0] += tv.x * xv; at[i4 * 4 + 1] += tv.y * xv;
        at[i4 * 4 + 2] += tv.z * xv; at[i4 * 4 + 3] += tv.w * xv;
        ap[i4 * 4 + 0] += pv.x * xv; ap[i4 * 4 + 1] += pv.y * xv;
        ap[i4 * 4 + 2] += pv.z * xv; ap[i4 * 4 + 3] += pv.w * xv;
      }
    }
  }
#pragma unroll
  for (int i = 0; i < 16; ++i) {
    int r = rbase + i;
    theta[((size_t)b * C8 + r) * NN + n0 + col] = at[i] + tb[r];
    phi[((size_t)b * C8 + r) * NN + n0 + col] = ap[i] + pb[r];
  }
}

__global__ __launch_bounds__(256) void proj1_kernel(
    const float* __restrict__ x0,
    const float* __restrict__ gw, const float* __restrict__ gbias,
    float* __restrict__ g) {
  __shared__ float xs[64][64];
  __shared__ float wT[64][68];
  const int b = blockIdx.y;
  const int n0 = blockIdx.x * 64;
  const int t = threadIdx.x;
  const int col = t & 63;
  const int q4 = t >> 6;
  const int rbase = q4 * 16;
  const float* xb = x0 + (size_t)b * CC * NN;
  float ag[16];
#pragma unroll
  for (int i = 0; i < 16; ++i) ag[i] = 0.f;
  for (int k0 = 0; k0 < CC; k0 += 64) {
    __syncthreads();
#pragma unroll
    for (int j = 0; j < 16; ++j) {
      int kk = q4 + j * 4;
      xs[kk][col] = xb[(size_t)(k0 + kk) * NN + n0 + col];
      wT[col][kk] = gw[kk * CC + k0 + col];
    }
    __syncthreads();
#pragma unroll 4
    for (int kk = 0; kk < 64; ++kk) {
      float xv = xs[kk][col];
      const float4* qt = (const float4*)&wT[kk][rbase];
#pragma unroll
      for (int i4 = 0; i4 < 4; ++i4) {
        float4 tv = qt[i4];
        ag[i4 * 4 + 0] += tv.x * xv; ag[i4 * 4 + 1] += tv.y * xv;
        ag[i4 * 4 + 2] += tv.z * xv; ag[i4 * 4 + 3] += tv.w * xv;
      }
    }
  }
#pragma unroll
  for (int i = 0; i < 16; ++i) {
    int r = rbase + i;
    g[((size_t)b * C8 + r) * NN + n0 + col] = ag[i] + gbias[r];
  }
}

// ---------------------------------------------------------------------------
// Flash attention, fp32. Block = 256 threads (4 waves), 32 query rows/block.
// Wave w owns rows w*8..w*8+7; lane = key column m within the 64-wide tile.
// Q and P are stored transposed in LDS so the S/PV inner loops read them as
// float4 broadcasts (2 b128 + 1 b32 per 8 FMAs).
// ---------------------------------------------------------------------------
__global__ __launch_bounds__(256) void attn_kernel(
    const float* __restrict__ theta, const float* __restrict__ phi,
    const float* __restrict__ g, float* __restrict__ y) {
  __shared__ float Qt[64][36];   // Qt[c][r], r in [0,32) — 36 is fine here
  __shared__ float Ks[64][64];   // Ks[c][mm]
  __shared__ float Vs[64][65];   // Vs[mm][c]  (pad -> conflict-free transpose write)
  __shared__ float Pt[64][36];   // Pt[mm][r], r in [0,32)
  const int b = blockIdx.y;
  const int n0 = blockIdx.x * 32;
  const int t = threadIdx.x;
  const int lane = t & 63;
  const int w = t >> 6;
  const float* thb = theta + (size_t)b * C8 * NN;
  const float* phb = phi + (size_t)b * C8 * NN;
  const float* gb = g + (size_t)b * C8 * NN;
  {
    int r = t & 31;
    int cbase = t >> 5;  // 0..7
#pragma unroll
    for (int j = 0; j < 8; ++j) {
      int c = cbase + j * 8;
      Qt[c][r] = phb[(size_t)c * NN + n0 + r];
    }
  }
  float m_run[8], l_run[8], acc[8];
#pragma unroll
  for (int i = 0; i < 8; ++i) { m_run[i] = -1e30f; l_run[i] = 0.f; acc[i] = 0.f; }
  __syncthreads();

  for (int m0 = 0; m0 < NN; m0 += 64) {
#pragma unroll
    for (int j = 0; j < 16; ++j) {
      int c = (t >> 6) + j * 4;
      int mm = t & 63;
      Ks[c][mm] = thb[(size_t)c * NN + m0 + mm];
      Vs[mm][c] = gb[(size_t)c * NN + m0 + mm];
    }
    __syncthreads();

    float s_[8];
#pragma unroll
    for (int i = 0; i < 8; ++i) s_[i] = 0.f;
#pragma unroll 2
    for (int c = 0; c < 64; ++c) {
      float kv = Ks[c][lane];
      const float4* qp = (const float4*)&Qt[c][w * 8];
      float4 q0 = qp[0], q1 = qp[1];
      s_[0] += q0.x * kv; s_[1] += q0.y * kv; s_[2] += q0.z * kv; s_[3] += q0.w * kv;
      s_[4] += q1.x * kv; s_[5] += q1.y * kv; s_[6] += q1.z * kv; s_[7] += q1.w * kv;
    }
    // online softmax per row (row spans the 64 lanes of this wave)
#pragma unroll
    for (int i = 0; i < 8; ++i) {
      float rm = s_[i];
#pragma unroll
      for (int off = 32; off >= 1; off >>= 1) rm = fmaxf(rm, __shfl_xor(rm, off));
      float mn = fmaxf(m_run[i], rm);
      float sc = __expf(m_run[i] - mn);
      float p = __expf(s_[i] - mn);
      float rs = p;
#pragma unroll
      for (int off = 32; off >= 1; off >>= 1) rs += __shfl_xor(rs, off);
      l_run[i] = l_run[i] * sc + rs;
      acc[i] *= sc;
      m_run[i] = mn;
      Pt[lane][w * 8 + i] = p;   // wave-private columns: no cross-wave hazard
    }
    // PV
#pragma unroll 2
    for (int mm = 0; mm < 64; ++mm) {
      float vv = Vs[mm][lane];
      const float4* pp = (const float4*)&Pt[mm][w * 8];
      float4 p0 = pp[0], p1 = pp[1];
      acc[0] += p0.x * vv; acc[1] += p0.y * vv; acc[2] += p0.z * vv; acc[3] += p0.w * vv;
      acc[4] += p1.x * vv; acc[5] += p1.y * vv; acc[6] += p1.z * vv; acc[7] += p1.w * vv;
    }
    __syncthreads();
  }
#pragma unroll
  for (int i = 0; i < 8; ++i) {
    int r = n0 + w * 8 + i;
    y[((size_t)b * NN + r) * C8 + lane] = acc[i] / l_run[i];
  }
}

// ---------------------------------------------------------------------------
// W_y stats via Gram matrix: G[b][k][k2] = sum_m yflat[k*4096+m]*yflat[k2*4096+m]
// ---------------------------------------------------------------------------
__global__ void zero_kernel(float* __restrict__ p, int n) {
  int i = blockIdx.x * blockDim.x + threadIdx.x;
  if (i < n) p[i] = 0.f;
}

__global__ __launch_bounds__(256) void gram_kernel(const float* __restrict__ y,
                                                   float* __restrict__ Gm) {
  __shared__ float ys[64][65];
  const int b = blockIdx.y;
  const int m0 = blockIdx.x * 64;
  const int t = threadIdx.x;
  const float* yb = y + (size_t)b * (NN * C8);
#pragma unroll
  for (int j = 0; j < 16; ++j) {
    int k = (t >> 6) + j * 4;
    ys[k][t & 63] = yb[(size_t)k * NN + m0 + (t & 63)];
  }
  __syncthreads();
  const int k = t >> 2;
  const int k2b = (t & 3) * 16;
  float a_[16];
#pragma unroll
  for (int i = 0; i < 16; ++i) a_[i] = 0.f;
  for (int m = 0; m < 64; ++m) {
    float av = ys[k][m];
#pragma unroll
    for (int i = 0; i < 16; ++i) a_[i] += av * ys[k2b + i][m];
  }
#pragma unroll
  for (int i = 0; i < 16; ++i)
    atomicAdd(&Gm[(size_t)b * 4096 + k * 64 + k2b + i], a_[i]);
}

__global__ __launch_bounds__(64) void ybar_kernel(const float* __restrict__ y,
                                                  float* __restrict__ yb) {
  const int k = blockIdx.x, b = blockIdx.y, l = threadIdx.x;
  const float* row = y + (size_t)b * (NN * C8) + (size_t)k * NN;
  float s = 0.f;
  for (int j = l; j < NN; j += 64) s += row[j];
#pragma unroll
  for (int off = 32; off >= 1; off >>= 1) s += __shfl_xor(s, off);
  if (l == 0) yb[b * 64 + k] = s * (1.f / NN);
}

__global__ __launch_bounds__(64) void wy_stats_kernel(
    const float* __restrict__ Gm, const float* __restrict__ ybar,
    const float* __restrict__ Ww, const float* __restrict__ Wb,
    float* __restrict__ mu_s, float* __restrict__ std_s) {
  __shared__ float ww[64];
  const int o = blockIdx.x, b = blockIdx.y, l = threadIdx.x;
  ww[l] = Ww[o * 64 + l];
  __syncthreads();
  const float* Gb = Gm + (size_t)b * 4096;
  float colsum = 0.f;
  for (int k = 0; k < 64; ++k) colsum += ww[k] * Gb[k * 64 + l];
  float qq = ww[l] * colsum;
  float md = ww[l] * ybar[b * 64 + l];
#pragma unroll
  for (int off = 32; off >= 1; off >>= 1) {
    qq += __shfl_xor(qq, off);
    md += __shfl_xor(md, off);
  }
  if (l == 0) {
    float bias = Wb[o];
    float mu = md + bias;
    float ex2 = qq * (1.f / NN) + 2.f * bias * md + bias * bias;
    float var = ex2 - mu * mu;
    mu_s[b * CC + o] = mu;
    std_s[b * CC + o] = sqrtf(fmaxf(var, 0.f) + EPSI);
  }
}

// ---------------------------------------------------------------------------
// x0 instance stats + fused AdaIN epilogue
// ---------------------------------------------------------------------------
__global__ __launch_bounds__(256) void x_stats_kernel(const float* __restrict__ x0,
                                                      float* __restrict__ mu_c,
                                                      float* __restrict__ rstd_c) {
  __shared__ float redA[4], redB[4];
  const int c = blockIdx.x, b = blockIdx.y, t = threadIdx.x;
  const float4* xi = (const float4*)(x0 + ((size_t)b * CC + c) * NN);
  float s1 = 0.f, s2 = 0.f;
#pragma unroll
  for (int j = t; j < NN / 4; j += 256) {
    float4 v = xi[j];
    s1 += v.x + v.y + v.z + v.w;
    s2 += v.x * v.x + v.y * v.y + v.z * v.z + v.w * v.w;
  }
#pragma unroll
  for (int off = 32; off >= 1; off >>= 1) {
    s1 += __shfl_xor(s1, off);
    s2 += __shfl_xor(s2, off);
  }
  if ((t & 63) == 0) { redA[t >> 6] = s1; redB[t >> 6] = s2; }
  __syncthreads();
  if (t == 0) {
    float S1 = redA[0] + redA[1] + redA[2] + redA[3];
    float S2 = redB[0] + redB[1] + redB[2] + redB[3];
    float mean = S1 * (1.f / NN);
    float var = S2 * (1.f / NN) - mean * mean;
    mu_c[b * CC + c] = mean;
    rstd_c[b * CC + c] = 1.f / sqrtf(var + EPSI);
  }
}

__global__ __launch_bounds__(256) void adain_kernel(
    const float* __restrict__ x0, const float* __restrict__ mu_c,
    const float* __restrict__ rstd_c, const float* __restrict__ mu_s,
    const float* __restrict__ std_s, float* __restrict__ out) {
  const int c = blockIdx.x, b = blockIdx.y, t = threadIdx.x;
  const int bc = b * CC + c;
  const float scale = std_s[bc] * rstd_c[bc];
  const float shift = mu_s[bc] - scale * mu_c[bc];
  const float4* xi = (const float4*)(x0 + (size_t)bc * NN);
  float4* oo = (float4*)(out + (size_t)bc * NN);
#pragma unroll
  for (int j = t; j < NN / 4; j += 256) {
    float4 v = xi[j];
    v.x = v.x * scale + shift;
    v.y = v.y * scale + shift;
    v.z = v.z * scale + shift;
    v.w = v.w * scale + shift;
    oo[j] = v;
  }
}

extern "C" void kernel_launch(void* const* d_in, const int* in_sizes, int n_in,
                              void* d_out, int out_size, void* d_ws, size_t ws_size,
                              hipStream_t stream) {
  (void)in_sizes; (void)n_in; (void)out_size; (void)ws_size;
  const float* x0 = (const float*)d_in[0];
  const float* x1 = (const float*)d_in[1];
  const float* g_w = (const float*)d_in[2];
  const float* g_b = (const float*)d_in[3];
  const float* theta_w = (const float*)d_in[4];
  const float* theta_b = (const float*)d_in[5];
  const float* phi_w = (const float*)d_in[6];
  const float* phi_b = (const float*)d_in[7];
  const float* W_w = (const float*)d_in[8];
  const float* W_b = (const float*)d_in[9];
  float* out = (float*)d_out;
  float* ws = (float*)d_ws;

  float* theta = ws;                 // [B][C8][N]   1048576
  float* phi = ws + 1048576;         // [B][C8][N]   1048576
  float* g = ws + 2097152;           // [B][C8][N]   1048576
  float* y = ws + 3145728;           // [B][N][C8]   1048576
  float* Gm = ws + 4194304;          // [B][64][64]  16384
  float* yb = ws + 4210688;          // [B][64]      256
  float* mu_s = ws + 4210944;        // [B][C]       2048
  float* std_s = ws + 4212992;       // [B][C]       2048
  float* mu_c = ws + 4215040;        // [B][C]       2048
  float* rstd_c = ws + 4217088;      // [B][C]       2048

  proj2_kernel<<<dim3(64, BB), 256, 0, stream>>>(x1, theta_w, theta_b, phi_w,
                                                 phi_b, theta, phi);
  proj1_kernel<<<dim3(64, BB), 256, 0, stream>>>(x0, g_w, g_b, g);
  attn_kernel<<<dim3(128, BB), 256, 0, stream>>>(theta, phi, g, y);
  zero_kernel<<<dim3(64), 256, 0, stream>>>(Gm, BB * 64 * 64);
  gram_kernel<<<dim3(64, BB), 256, 0, stream>>>(y, Gm);
  ybar_kernel<<<dim3(64, BB), 64, 0, stream>>>(y, yb);
  wy_stats_kernel<<<dim3(CC, BB), 64, 0, stream>>>(Gm, yb, W_w, W_b, mu_s, std_s);
  x_stats_kernel<<<dim3(CC, BB), 256, 0, stream>>>(x0, mu_c, rstd_c);
  adain_kernel<<<dim3(CC, BB), 256, 0, stream>>>(x0, mu_c, rstd_c, mu_s, std_s, out);
}

// Round 4
// 499.566 us; speedup vs baseline: 1.6940x; 1.6940x over previous
//
#include <hip/hip_runtime.h>

#define BB 4
#define CC 512
#define C8 64
#define NN 4096
#define EPSI 1e-5f

typedef unsigned short ushort_t;
typedef unsigned int uint;
typedef __bf16 bf16x8 __attribute__((ext_vector_type(8)));
typedef float f32x4 __attribute__((ext_vector_type(4)));

__device__ inline ushort_t f2bf(float f) {
  uint u = __float_as_uint(f);
  uint r = (u + 0x7FFFu + ((u >> 16) & 1u)) >> 16;  // RNE
  return (ushort_t)r;
}

__device__ inline bf16x8 ld_bf8(const ushort_t* p) {
  uint4 u = *(const uint4*)p;
  return __builtin_bit_cast(bf16x8, u);
}

// ---------------------------------------------------------------------------
// proj2: theta/phi projections of x1, output bf16 TRANSPOSED [B][N][C8]
// (n-major: the MFMA A/B fragment-friendly layout for the attention kernel).
// ---------------------------------------------------------------------------
__global__ __launch_bounds__(256) void proj2_kernel(
    const float* __restrict__ x1,
    const float* __restrict__ tw, const float* __restrict__ tb,
    const float* __restrict__ pw, const float* __restrict__ pb,
    ushort_t* __restrict__ thetaT, ushort_t* __restrict__ phiT) {
  __shared__ float xs[64][64];
  __shared__ float wtT[64][68];   // 64 out-channels + 4 pad (round-1 fix)
  __shared__ float wpT[64][68];
  const int b = blockIdx.y;
  const int n0 = blockIdx.x * 64;
  const int t = threadIdx.x;
  const int col = t & 63;
  const int q4 = t >> 6;
  const int rbase = q4 * 16;
  const float* xb = x1 + (size_t)b * CC * NN;
  float at[16], ap[16];
#pragma unroll
  for (int i = 0; i < 16; ++i) { at[i] = 0.f; ap[i] = 0.f; }
  for (int k0 = 0; k0 < CC; k0 += 64) {
    __syncthreads();
#pragma unroll
    for (int j = 0; j < 16; ++j) {
      int kk = q4 + j * 4;
      xs[kk][col] = xb[(size_t)(k0 + kk) * NN + n0 + col];
      wtT[col][kk] = tw[kk * CC + k0 + col];
      wpT[col][kk] = pw[kk * CC + k0 + col];
    }
    __syncthreads();
#pragma unroll 4
    for (int kk = 0; kk < 64; ++kk) {
      float xv = xs[kk][col];
      const float4* qt = (const float4*)&wtT[kk][rbase];
      const float4* qp = (const float4*)&wpT[kk][rbase];
#pragma unroll
      for (int i4 = 0; i4 < 4; ++i4) {
        float4 tv = qt[i4];
        float4 pv = qp[i4];
        at[i4 * 4 + 0] += tv.x * xv; at[i4 * 4 + 1] += tv.y * xv;
        at[i4 * 4 + 2] += tv.z * xv; at[i4 * 4 + 3] += tv.w * xv;
        ap[i4 * 4 + 0] += pv.x * xv; ap[i4 * 4 + 1] += pv.y * xv;
        ap[i4 * 4 + 2] += pv.z * xv; ap[i4 * 4 + 3] += pv.w * xv;
      }
    }
  }
  const size_t nIdx = (size_t)b * NN + n0 + col;
  uint pk[8];
#pragma unroll
  for (int j = 0; j < 8; ++j)
    pk[j] = (uint)f2bf(at[2 * j] + tb[rbase + 2 * j]) |
            ((uint)f2bf(at[2 * j + 1] + tb[rbase + 2 * j + 1]) << 16);
  {
    uint4* dst = (uint4*)(thetaT + nIdx * 64 + rbase);
    dst[0] = make_uint4(pk[0], pk[1], pk[2], pk[3]);
    dst[1] = make_uint4(pk[4], pk[5], pk[6], pk[7]);
  }
#pragma unroll
  for (int j = 0; j < 8; ++j)
    pk[j] = (uint)f2bf(ap[2 * j] + pb[rbase + 2 * j]) |
            ((uint)f2bf(ap[2 * j + 1] + pb[rbase + 2 * j + 1]) << 16);
  {
    uint4* dst = (uint4*)(phiT + nIdx * 64 + rbase);
    dst[0] = make_uint4(pk[0], pk[1], pk[2], pk[3]);
    dst[1] = make_uint4(pk[4], pk[5], pk[6], pk[7]);
  }
}

// ---------------------------------------------------------------------------
// proj1: g projection of x0, output bf16 NATURAL [B][C8][N]
// (c-major: the PV A-fragment layout).
// ---------------------------------------------------------------------------
__global__ __launch_bounds__(256) void proj1_kernel(
    const float* __restrict__ x0,
    const float* __restrict__ gw, const float* __restrict__ gbias,
    ushort_t* __restrict__ g) {
  __shared__ float xs[64][64];
  __shared__ float wT[64][68];
  const int b = blockIdx.y;
  const int n0 = blockIdx.x * 64;
  const int t = threadIdx.x;
  const int col = t & 63;
  const int q4 = t >> 6;
  const int rbase = q4 * 16;
  const float* xb = x0 + (size_t)b * CC * NN;
  float ag[16];
#pragma unroll
  for (int i = 0; i < 16; ++i) ag[i] = 0.f;
  for (int k0 = 0; k0 < CC; k0 += 64) {
    __syncthreads();
#pragma unroll
    for (int j = 0; j < 16; ++j) {
      int kk = q4 + j * 4;
      xs[kk][col] = xb[(size_t)(k0 + kk) * NN + n0 + col];
      wT[col][kk] = gw[kk * CC + k0 + col];
    }
    __syncthreads();
#pragma unroll 4
    for (int kk = 0; kk < 64; ++kk) {
      float xv = xs[kk][col];
      const float4* qt = (const float4*)&wT[kk][rbase];
#pragma unroll
      for (int i4 = 0; i4 < 4; ++i4) {
        float4 tv = qt[i4];
        ag[i4 * 4 + 0] += tv.x * xv; ag[i4 * 4 + 1] += tv.y * xv;
        ag[i4 * 4 + 2] += tv.z * xv; ag[i4 * 4 + 3] += tv.w * xv;
      }
    }
  }
#pragma unroll
  for (int i = 0; i < 16; ++i) {
    int r = rbase + i;
    g[((size_t)b * C8 + r) * NN + n0 + col] = f2bf(ag[i] + gbias[r]);
  }
}

// ---------------------------------------------------------------------------
// MFMA flash attention. 128 threads (2 waves), 32 q-rows/block, m-tiles of 64.
// Swapped QK^T: S^T[m][q] = theta^T[m][:] . phi^T[q][:]  (D col = q = lane&15,
// so softmax rows are lane-local: in-register reduce + 2 shfl_xor).
// PV: y^T[c][q] = g[c][:] . P^T[:][q]; P goes through a wave-private
// XOR-swizzled LDS buffer (write b64 pairs, read b128 B-frags). No barriers
// in the m-loop; A/B frags load straight from global (L2-resident).
// ---------------------------------------------------------------------------
__global__ __launch_bounds__(128) void attn_mfma_kernel(
    const ushort_t* __restrict__ thT,  // [B][N][64] bf16 (n-major)
    const ushort_t* __restrict__ phT,  // [B][N][64] bf16 (n-major)
    const ushort_t* __restrict__ gm,   // [B][64][N] bf16 (c-major)
    float* __restrict__ y) {           // [B][N][64] f32
  __shared__ char Plds[2][2048];       // per-wave P^T tile [16q][64m] bf16, swizzled
  const int b = blockIdx.y;
  const int q0 = blockIdx.x * 32;
  const int tid = threadIdx.x;
  const int l = tid & 63;
  const int w = tid >> 6;
  const int l15 = l & 15;
  const int lg = l >> 4;
  const ushort_t* thB = thT + (size_t)b * NN * 64;
  const ushort_t* phB = phT + (size_t)b * NN * 64;
  const ushort_t* gB = gm + (size_t)b * 64 * NN;
  char* Pw = Plds[w];

  // hoisted Q (phi) B-frags: B[k=c][col=q], k-chunks of 32
  bf16x8 qf[2];
  {
    const ushort_t* p = phB + (size_t)(q0 + w * 16 + l15) * 64 + lg * 8;
    qf[0] = ld_bf8(p);
    qf[1] = ld_bf8(p + 32);
  }

  float m_run = -1e30f, l_run = 0.f;
  f32x4 acc[4];
#pragma unroll
  for (int s = 0; s < 4; ++s) acc[s] = {0.f, 0.f, 0.f, 0.f};

  const ushort_t* thL = thB + (size_t)l15 * 64 + lg * 8;   // + (m0+16s)*64 + 32k
  const ushort_t* gL = gB + (size_t)l15 * 4096 + lg * 8;   // + s*16*4096 + m0 + 32k
  const int pwr = l15 * 128;                               // P row byte base (q row)
  const uint pswz = (uint)((l & 7) << 4);                  // XOR swizzle mask

  for (int m0 = 0; m0 < NN; m0 += 64) {
    // ---- QK^T: S^T tile [64m][16q], 4 m-subtiles x 2 k-steps ----
    f32x4 st[4];
#pragma unroll
    for (int s = 0; s < 4; ++s) st[s] = {0.f, 0.f, 0.f, 0.f};
#pragma unroll
    for (int s = 0; s < 4; ++s) {
      const ushort_t* ts = thL + (size_t)(m0 + 16 * s) * 64;
      bf16x8 a0 = ld_bf8(ts);
      bf16x8 a1 = ld_bf8(ts + 32);
      st[s] = __builtin_amdgcn_mfma_f32_16x16x32_bf16(a0, qf[0], st[s], 0, 0, 0);
      st[s] = __builtin_amdgcn_mfma_f32_16x16x32_bf16(a1, qf[1], st[s], 0, 0, 0);
    }
    // ---- g A-frags issued early (consumed after softmax) ----
    bf16x8 ga[4][2];
#pragma unroll
    for (int s = 0; s < 4; ++s) {
      const ushort_t* gs = gL + (size_t)s * 16 * 4096 + m0;
      ga[s][0] = ld_bf8(gs);
      ga[s][1] = ld_bf8(gs + 32);
    }
    // ---- online softmax (rows lane-local: 16 vals + xor16/xor32) ----
    float tmax = -1e30f;
#pragma unroll
    for (int s = 0; s < 4; ++s)
#pragma unroll
      for (int r = 0; r < 4; ++r) tmax = fmaxf(tmax, st[s][r]);
    tmax = fmaxf(tmax, __shfl_xor(tmax, 16));
    tmax = fmaxf(tmax, __shfl_xor(tmax, 32));
    const float mn = fmaxf(m_run, tmax);
    const float sc = __expf(m_run - mn);
    float tsum = 0.f;
#pragma unroll
    for (int s = 0; s < 4; ++s)
#pragma unroll
      for (int r = 0; r < 4; ++r) {
        float p = __expf(st[s][r] - mn);
        st[s][r] = p;
        tsum += p;
      }
    tsum += __shfl_xor(tsum, 16);
    tsum += __shfl_xor(tsum, 32);
    l_run = l_run * sc + tsum;
    m_run = mn;
#pragma unroll
    for (int s = 0; s < 4; ++s) acc[s] *= sc;
    // ---- P -> bf16 -> swizzled wave-private LDS ([q][m] layout) ----
#pragma unroll
    for (int s = 0; s < 4; ++s) {
      uint d0, d1;
      float a0 = st[s][0], a1 = st[s][1], a2 = st[s][2], a3 = st[s][3];
      asm("v_cvt_pk_bf16_f32 %0, %1, %2" : "=v"(d0) : "v"(a0), "v"(a1));
      asm("v_cvt_pk_bf16_f32 %0, %1, %2" : "=v"(d1) : "v"(a2), "v"(a3));
      const uint mb = (uint)((16 * s + lg * 4) * 2);  // byte offset of m0-elem
      char* wp = Pw + pwr + (int)((mb & 15u) | ((mb & ~15u) ^ pswz));
      unsigned long long v = (unsigned long long)d0 | ((unsigned long long)d1 << 32);
      *(unsigned long long*)wp = v;
    }
    // ---- PV: y^T += g . P^T ----
#pragma unroll
    for (int k = 0; k < 2; ++k) {
      const uint rb = (uint)(lg * 16 + 64 * k);
      bf16x8 pbf = ld_bf8((const ushort_t*)(Pw + pwr + (int)(rb ^ pswz)));
#pragma unroll
      for (int s = 0; s < 4; ++s)
        acc[s] = __builtin_amdgcn_mfma_f32_16x16x32_bf16(ga[s][k], pbf, acc[s], 0, 0, 0);
    }
  }
  // ---- epilogue: y[q][c] = acc/l_run (lane q = l15; c = 16s + lg*4 + r) ----
  const float inv = 1.f / l_run;
  float* yB = y + ((size_t)b * NN + q0 + w * 16 + l15) * 64;
#pragma unroll
  for (int s = 0; s < 4; ++s) {
    float4 o;
    o.x = acc[s][0] * inv;
    o.y = acc[s][1] * inv;
    o.z = acc[s][2] * inv;
    o.w = acc[s][3] * inv;
    *(float4*)(yB + 16 * s + lg * 4) = o;
  }
}

// ---------------------------------------------------------------------------
// W_y stats via Gram matrix (y stays fp32; flat [64][4096] channel view).
// ---------------------------------------------------------------------------
__global__ void zero_kernel(float* __restrict__ p, int n) {
  int i = blockIdx.x * blockDim.x + threadIdx.x;
  if (i < n) p[i] = 0.f;
}

__global__ __launch_bounds__(256) void gram_kernel(const float* __restrict__ y,
                                                   float* __restrict__ Gm) {
  __shared__ float ys[64][65];
  const int b = blockIdx.y;
  const int m0 = blockIdx.x * 64;
  const int t = threadIdx.x;
  const float* yb = y + (size_t)b * (NN * C8);
#pragma unroll
  for (int j = 0; j < 16; ++j) {
    int k = (t >> 6) + j * 4;
    ys[k][t & 63] = yb[(size_t)k * NN + m0 + (t & 63)];
  }
  __syncthreads();
  const int k = t >> 2;
  const int k2b = (t & 3) * 16;
  float a_[16];
#pragma unroll
  for (int i = 0; i < 16; ++i) a_[i] = 0.f;
  for (int m = 0; m < 64; ++m) {
    float av = ys[k][m];
#pragma unroll
    for (int i = 0; i < 16; ++i) a_[i] += av * ys[k2b + i][m];
  }
#pragma unroll
  for (int i = 0; i < 16; ++i)
    atomicAdd(&Gm[(size_t)b * 4096 + k * 64 + k2b + i], a_[i]);
}

__global__ __launch_bounds__(64) void ybar_kernel(const float* __restrict__ y,
                                                  float* __restrict__ yb) {
  const int k = blockIdx.x, b = blockIdx.y, l = threadIdx.x;
  const float* row = y + (size_t)b * (NN * C8) + (size_t)k * NN;
  float s = 0.f;
  for (int j = l; j < NN; j += 64) s += row[j];
#pragma unroll
  for (int off = 32; off >= 1; off >>= 1) s += __shfl_xor(s, off);
  if (l == 0) yb[b * 64 + k] = s * (1.f / NN);
}

__global__ __launch_bounds__(64) void wy_stats_kernel(
    const float* __restrict__ Gm, const float* __restrict__ ybar,
    const float* __restrict__ Ww, const float* __restrict__ Wb,
    float* __restrict__ mu_s, float* __restrict__ std_s) {
  __shared__ float ww[64];
  const int o = blockIdx.x, b = blockIdx.y, l = threadIdx.x;
  ww[l] = Ww[o * 64 + l];
  __syncthreads();
  const float* Gb = Gm + (size_t)b * 4096;
  float colsum = 0.f;
  for (int k = 0; k < 64; ++k) colsum += ww[k] * Gb[k * 64 + l];
  float qq = ww[l] * colsum;
  float md = ww[l] * ybar[b * 64 + l];
#pragma unroll
  for (int off = 32; off >= 1; off >>= 1) {
    qq += __shfl_xor(qq, off);
    md += __shfl_xor(md, off);
  }
  if (l == 0) {
    float bias = Wb[o];
    float mu = md + bias;
    float ex2 = qq * (1.f / NN) + 2.f * bias * md + bias * bias;
    float var = ex2 - mu * mu;
    mu_s[b * CC + o] = mu;
    std_s[b * CC + o] = sqrtf(fmaxf(var, 0.f) + EPSI);
  }
}

// ---------------------------------------------------------------------------
// x0 instance stats + AdaIN epilogue
// ---------------------------------------------------------------------------
__global__ __launch_bounds__(256) void x_stats_kernel(const float* __restrict__ x0,
                                                      float* __restrict__ mu_c,
                                                      float* __restrict__ rstd_c) {
  __shared__ float redA[4], redB[4];
  const int c = blockIdx.x, b = blockIdx.y, t = threadIdx.x;
  const float4* xi = (const float4*)(x0 + ((size_t)b * CC + c) * NN);
  float s1 = 0.f, s2 = 0.f;
#pragma unroll
  for (int j = t; j < NN / 4; j += 256) {
    float4 v = xi[j];
    s1 += v.x + v.y + v.z + v.w;
    s2 += v.x * v.x + v.y * v.y + v.z * v.z + v.w * v.w;
  }
#pragma unroll
  for (int off = 32; off >= 1; off >>= 1) {
    s1 += __shfl_xor(s1, off);
    s2 += __shfl_xor(s2, off);
  }
  if ((t & 63) == 0) { redA[t >> 6] = s1; redB[t >> 6] = s2; }
  __syncthreads();
  if (t == 0) {
    float S1 = redA[0] + redA[1] + redA[2] + redA[3];
    float S2 = redB[0] + redB[1] + redB[2] + redB[3];
    float mean = S1 * (1.f / NN);
    float var = S2 * (1.f / NN) - mean * mean;
    mu_c[b * CC + c] = mean;
    rstd_c[b * CC + c] = 1.f / sqrtf(var + EPSI);
  }
}

__global__ __launch_bounds__(256) void adain_kernel(
    const float* __restrict__ x0, const float* __restrict__ mu_c,
    const float* __restrict__ rstd_c, const float* __restrict__ mu_s,
    const float* __restrict__ std_s, float* __restrict__ out) {
  const int c = blockIdx.x, b = blockIdx.y, t = threadIdx.x;
  const int bc = b * CC + c;
  const float scale = std_s[bc] * rstd_c[bc];
  const float shift = mu_s[bc] - scale * mu_c[bc];
  const float4* xi = (const float4*)(x0 + (size_t)bc * NN);
  float4* oo = (float4*)(out + (size_t)bc * NN);
#pragma unroll
  for (int j = t; j < NN / 4; j += 256) {
    float4 v = xi[j];
    v.x = v.x * scale + shift;
    v.y = v.y * scale + shift;
    v.z = v.z * scale + shift;
    v.w = v.w * scale + shift;
    oo[j] = v;
  }
}

extern "C" void kernel_launch(void* const* d_in, const int* in_sizes, int n_in,
                              void* d_out, int out_size, void* d_ws, size_t ws_size,
                              hipStream_t stream) {
  (void)in_sizes; (void)n_in; (void)out_size; (void)ws_size;
  const float* x0 = (const float*)d_in[0];
  const float* x1 = (const float*)d_in[1];
  const float* g_w = (const float*)d_in[2];
  const float* g_b = (const float*)d_in[3];
  const float* theta_w = (const float*)d_in[4];
  const float* theta_b = (const float*)d_in[5];
  const float* phi_w = (const float*)d_in[6];
  const float* phi_b = (const float*)d_in[7];
  const float* W_w = (const float*)d_in[8];
  const float* W_b = (const float*)d_in[9];
  float* out = (float*)d_out;
  float* ws = (float*)d_ws;

  ushort_t* thetaT = (ushort_t*)ws;              // [B][N][64] bf16 = 524288 f
  ushort_t* phiT = (ushort_t*)(ws + 524288);     // [B][N][64] bf16
  ushort_t* gbf = (ushort_t*)(ws + 1048576);     // [B][64][N] bf16
  float* y = ws + 1572864;                       // [B][N][64] f32 = 1048576 f
  float* Gm = ws + 2621440;                      // [B][64][64]
  float* yb = ws + 2637824;                      // [B][64]
  float* mu_s = ws + 2638080;                    // [B][C]
  float* std_s = ws + 2640128;
  float* mu_c = ws + 2642176;
  float* rstd_c = ws + 2644224;

  proj2_kernel<<<dim3(64, BB), 256, 0, stream>>>(x1, theta_w, theta_b, phi_w,
                                                 phi_b, thetaT, phiT);
  proj1_kernel<<<dim3(64, BB), 256, 0, stream>>>(x0, g_w, g_b, gbf);
  attn_mfma_kernel<<<dim3(128, BB), 128, 0, stream>>>(thetaT, phiT, gbf, y);
  zero_kernel<<<dim3(64), 256, 0, stream>>>(Gm, BB * 64 * 64);
  gram_kernel<<<dim3(64, BB), 256, 0, stream>>>(y, Gm);
  ybar_kernel<<<dim3(64, BB), 64, 0, stream>>>(y, yb);
  wy_stats_kernel<<<dim3(CC, BB), 64, 0, stream>>>(Gm, yb, W_w, W_b, mu_s, std_s);
  x_stats_kernel<<<dim3(CC, BB), 256, 0, stream>>>(x0, mu_c, rstd_c);
  adain_kernel<<<dim3(CC, BB), 256, 0, stream>>>(x0, mu_c, rstd_c, mu_s, std_s, out);
}

// Round 8
// 355.580 us; speedup vs baseline: 2.3800x; 1.4049x over previous
//
#include <hip/hip_runtime.h>

#define BB 4
#define CC 512
#define C8 64
#define NN 4096
#define EPSI 1e-5f

typedef unsigned short ushort_t;
typedef unsigned int uint;
typedef __bf16 bf16x8 __attribute__((ext_vector_type(8)));
typedef float f32x4 __attribute__((ext_vector_type(4)));

__device__ inline ushort_t f2bf(float f) {
  uint u = __float_as_uint(f);
  uint r = (u + 0x7FFFu + ((u >> 16) & 1u)) >> 16;  // RNE
  return (ushort_t)r;
}

__device__ inline bf16x8 ld_bf8(const ushort_t* p) {
  uint4 u = *(const uint4*)p;
  return __builtin_bit_cast(bf16x8, u);
}

// ---------------------------------------------------------------------------
// Weight fp32 -> bf16 convert (layout [r][512], k-contiguous: A-frag ready).
// blocks 0-31: theta_w, 32-63: phi_w, 64-95: g_w. 256 thr x 4 elems.
// ---------------------------------------------------------------------------
__global__ __launch_bounds__(256) void wconv_kernel(
    const float* __restrict__ tw, const float* __restrict__ pw,
    const float* __restrict__ gw, ushort_t* __restrict__ twb,
    ushort_t* __restrict__ pwb, ushort_t* __restrict__ gwb) {
  const int sec = blockIdx.x >> 5;
  const int idx = ((blockIdx.x & 31) * 256 + threadIdx.x) * 4;
  const float* src = sec == 0 ? tw : (sec == 1 ? pw : gw);
  ushort_t* dst = sec == 0 ? twb : (sec == 1 ? pwb : gwb);
  float4 v = *(const float4*)(src + idx);
  uint2 pk;
  pk.x = (uint)f2bf(v.x) | ((uint)f2bf(v.y) << 16);
  pk.y = (uint)f2bf(v.z) | ((uint)f2bf(v.w) << 16);
  *(uint2*)(dst + idx) = pk;
}

// ---------------------------------------------------------------------------
// MFMA projection of x1 -> thetaT, phiT  [B][N][64] bf16 (n-major).
// Per block: n-tile 32, K-loop 64. x tile [64k][32n] fp32 -> bf16 ->
// chunk-XOR-swizzled LDS xT[32n][64k]. Wave w: ns = w&1 (16 n), out = w>>1.
// D[row=r][col=n]: A = w bf16 frag (global, L2), B = xT frag (LDS b128).
// ---------------------------------------------------------------------------
__global__ __launch_bounds__(256) void proj2_mfma_kernel(
    const float* __restrict__ x1,
    const ushort_t* __restrict__ twb, const float* __restrict__ tb,
    const ushort_t* __restrict__ pwb, const float* __restrict__ pb,
    ushort_t* __restrict__ thetaT, ushort_t* __restrict__ phiT) {
  __shared__ char xT[32 * 128];   // [32 n][64 k] bf16, 16B-chunk XOR swizzle
  const int b = blockIdx.y;
  const int n0 = blockIdx.x * 32;
  const int t = threadIdx.x;
  const int l = t & 63;
  const int w = t >> 6;
  const int l15 = l & 15;
  const int lg = l >> 4;
  const int ns = w & 1;
  const int isphi = w >> 1;
  const float* xb = x1 + (size_t)b * CC * NN;
  const ushort_t* wb = isphi ? pwb : twb;
  const float* bias = isphi ? pb : tb;
  ushort_t* outp = isphi ? phiT : thetaT;

  f32x4 acc[4];
#pragma unroll
  for (int s = 0; s < 4; ++s) acc[s] = {0.f, 0.f, 0.f, 0.f};

  const int ldrow = t >> 3;   // 0..31
  const int ldc4 = t & 7;
  const int nfr = ns * 16 + l15;                       // frag n row
  const int fchunkbase = nfr * 128;
  for (int k0 = 0; k0 < CC; k0 += 64) {
    __syncthreads();
#pragma unroll
    for (int p = 0; p < 2; ++p) {
      const int kr = ldrow + p * 32;
      float4 v = *(const float4*)(xb + (size_t)(k0 + kr) * NN + n0 + ldc4 * 4);
      ushort_t e0 = f2bf(v.x), e1 = f2bf(v.y), e2 = f2bf(v.z), e3 = f2bf(v.w);
      const int chunk = kr >> 3;
      const int kin = (kr & 7) * 2;
#pragma unroll
      for (int j = 0; j < 4; ++j) {
        const int n = ldc4 * 4 + j;
        ushort_t e = j == 0 ? e0 : (j == 1 ? e1 : (j == 2 ? e2 : e3));
        *(ushort_t*)(xT + n * 128 + (((chunk ^ (n & 7)) << 4) | kin)) = e;
      }
    }
    __syncthreads();
#pragma unroll
    for (int ks = 0; ks < 2; ++ks) {
      bf16x8 bx = *(const bf16x8*)(xT + fchunkbase +
                                   (((ks * 4 + lg) ^ (nfr & 7)) << 4));
#pragma unroll
      for (int rs = 0; rs < 4; ++rs) {
        bf16x8 aw = ld_bf8(wb + (size_t)(rs * 16 + l15) * 512 + k0 + ks * 32 + lg * 8);
        acc[rs] = __builtin_amdgcn_mfma_f32_16x16x32_bf16(aw, bx, acc[rs], 0, 0, 0);
      }
    }
  }
  const size_t nrow = (size_t)b * NN + n0 + ns * 16 + l15;
#pragma unroll
  for (int rs = 0; rs < 4; ++rs) {
    float4 bv = *(const float4*)(bias + rs * 16 + lg * 4);
    float a0 = acc[rs][0] + bv.x;
    float a1 = acc[rs][1] + bv.y;
    float a2 = acc[rs][2] + bv.z;
    float a3 = acc[rs][3] + bv.w;
    uint d0, d1;
    asm("v_cvt_pk_bf16_f32 %0, %1, %2" : "=v"(d0) : "v"(a0), "v"(a1));
    asm("v_cvt_pk_bf16_f32 %0, %1, %2" : "=v"(d1) : "v"(a2), "v"(a3));
    uint2 pk; pk.x = d0; pk.y = d1;
    *(uint2*)(outp + nrow * 64 + rs * 16 + lg * 4) = pk;
  }
}

// ---------------------------------------------------------------------------
// MFMA projection of x0 -> g [B][64][N] bf16 (c-major).
// Wave w: ns = w&1, rh = w>>1 (r-half). Same LDS transpose as proj2.
// ---------------------------------------------------------------------------
__global__ __launch_bounds__(256) void proj1_mfma_kernel(
    const float* __restrict__ x0,
    const ushort_t* __restrict__ gwb, const float* __restrict__ gbias,
    ushort_t* __restrict__ g) {
  __shared__ char xT[32 * 128];
  const int b = blockIdx.y;
  const int n0 = blockIdx.x * 32;
  const int t = threadIdx.x;
  const int l = t & 63;
  const int w = t >> 6;
  const int l15 = l & 15;
  const int lg = l >> 4;
  const int ns = w & 1;
  const int rh = w >> 1;
  const float* xb = x0 + (size_t)b * CC * NN;

  f32x4 acc[2];
#pragma unroll
  for (int s = 0; s < 2; ++s) acc[s] = {0.f, 0.f, 0.f, 0.f};

  const int ldrow = t >> 3;
  const int ldc4 = t & 7;
  const int nfr = ns * 16 + l15;
  const int fchunkbase = nfr * 128;
  for (int k0 = 0; k0 < CC; k0 += 64) {
    __syncthreads();
#pragma unroll
    for (int p = 0; p < 2; ++p) {
      const int kr = ldrow + p * 32;
      float4 v = *(const float4*)(xb + (size_t)(k0 + kr) * NN + n0 + ldc4 * 4);
      ushort_t e0 = f2bf(v.x), e1 = f2bf(v.y), e2 = f2bf(v.z), e3 = f2bf(v.w);
      const int chunk = kr >> 3;
      const int kin = (kr & 7) * 2;
#pragma unroll
      for (int j = 0; j < 4; ++j) {
        const int n = ldc4 * 4 + j;
        ushort_t e = j == 0 ? e0 : (j == 1 ? e1 : (j == 2 ? e2 : e3));
        *(ushort_t*)(xT + n * 128 + (((chunk ^ (n & 7)) << 4) | kin)) = e;
      }
    }
    __syncthreads();
#pragma unroll
    for (int ks = 0; ks < 2; ++ks) {
      bf16x8 bx = *(const bf16x8*)(xT + fchunkbase +
                                   (((ks * 4 + lg) ^ (nfr & 7)) << 4));
#pragma unroll
      for (int j = 0; j < 2; ++j) {
        const int rs = rh * 2 + j;
        bf16x8 aw = ld_bf8(gwb + (size_t)(rs * 16 + l15) * 512 + k0 + ks * 32 + lg * 8);
        acc[j] = __builtin_amdgcn_mfma_f32_16x16x32_bf16(aw, bx, acc[j], 0, 0, 0);
      }
    }
  }
  const int ncol = n0 + ns * 16 + l15;
#pragma unroll
  for (int j = 0; j < 2; ++j) {
    const int rbase = (rh * 2 + j) * 16 + lg * 4;
    float4 bv = *(const float4*)(gbias + rbase);
    g[((size_t)b * 64 + rbase + 0) * NN + ncol] = f2bf(acc[j][0] + bv.x);
    g[((size_t)b * 64 + rbase + 1) * NN + ncol] = f2bf(acc[j][1] + bv.y);
    g[((size_t)b * 64 + rbase + 2) * NN + ncol] = f2bf(acc[j][2] + bv.z);
    g[((size_t)b * 64 + rbase + 3) * NN + ncol] = f2bf(acc[j][3] + bv.w);
  }
}

// ---------------------------------------------------------------------------
// MFMA flash attention (unchanged from round 4).
// ---------------------------------------------------------------------------
__global__ __launch_bounds__(128) void attn_mfma_kernel(
    const ushort_t* __restrict__ thT,  // [B][N][64] bf16 (n-major)
    const ushort_t* __restrict__ phT,  // [B][N][64] bf16 (n-major)
    const ushort_t* __restrict__ gm,   // [B][64][N] bf16 (c-major)
    float* __restrict__ y) {           // [B][N][64] f32
  __shared__ char Plds[2][2048];
  const int b = blockIdx.y;
  const int q0 = blockIdx.x * 32;
  const int tid = threadIdx.x;
  const int l = tid & 63;
  const int w = tid >> 6;
  const int l15 = l & 15;
  const int lg = l >> 4;
  const ushort_t* thB = thT + (size_t)b * NN * 64;
  const ushort_t* phB = phT + (size_t)b * NN * 64;
  const ushort_t* gB = gm + (size_t)b * 64 * NN;
  char* Pw = Plds[w];

  bf16x8 qf[2];
  {
    const ushort_t* p = phB + (size_t)(q0 + w * 16 + l15) * 64 + lg * 8;
    qf[0] = ld_bf8(p);
    qf[1] = ld_bf8(p + 32);
  }

  float m_run = -1e30f, l_run = 0.f;
  f32x4 acc[4];
#pragma unroll
  for (int s = 0; s < 4; ++s) acc[s] = {0.f, 0.f, 0.f, 0.f};

  const ushort_t* thL = thB + (size_t)l15 * 64 + lg * 8;
  const ushort_t* gL = gB + (size_t)l15 * 4096 + lg * 8;
  const int pwr = l15 * 128;
  const uint pswz = (uint)((l & 7) << 4);

  for (int m0 = 0; m0 < NN; m0 += 64) {
    f32x4 st[4];
#pragma unroll
    for (int s = 0; s < 4; ++s) st[s] = {0.f, 0.f, 0.f, 0.f};
#pragma unroll
    for (int s = 0; s < 4; ++s) {
      const ushort_t* ts = thL + (size_t)(m0 + 16 * s) * 64;
      bf16x8 a0 = ld_bf8(ts);
      bf16x8 a1 = ld_bf8(ts + 32);
      st[s] = __builtin_amdgcn_mfma_f32_16x16x32_bf16(a0, qf[0], st[s], 0, 0, 0);
      st[s] = __builtin_amdgcn_mfma_f32_16x16x32_bf16(a1, qf[1], st[s], 0, 0, 0);
    }
    bf16x8 ga[4][2];
#pragma unroll
    for (int s = 0; s < 4; ++s) {
      const ushort_t* gs = gL + (size_t)s * 16 * 4096 + m0;
      ga[s][0] = ld_bf8(gs);
      ga[s][1] = ld_bf8(gs + 32);
    }
    float tmax = -1e30f;
#pragma unroll
    for (int s = 0; s < 4; ++s)
#pragma unroll
      for (int r = 0; r < 4; ++r) tmax = fmaxf(tmax, st[s][r]);
    tmax = fmaxf(tmax, __shfl_xor(tmax, 16));
    tmax = fmaxf(tmax, __shfl_xor(tmax, 32));
    const float mn = fmaxf(m_run, tmax);
    const float sc = __expf(m_run - mn);
    float tsum = 0.f;
#pragma unroll
    for (int s = 0; s < 4; ++s)
#pragma unroll
      for (int r = 0; r < 4; ++r) {
        float p = __expf(st[s][r] - mn);
        st[s][r] = p;
        tsum += p;
      }
    tsum += __shfl_xor(tsum, 16);
    tsum += __shfl_xor(tsum, 32);
    l_run = l_run * sc + tsum;
    m_run = mn;
#pragma unroll
    for (int s = 0; s < 4; ++s) acc[s] *= sc;
#pragma unroll
    for (int s = 0; s < 4; ++s) {
      uint d0, d1;
      float a0 = st[s][0], a1 = st[s][1], a2 = st[s][2], a3 = st[s][3];
      asm("v_cvt_pk_bf16_f32 %0, %1, %2" : "=v"(d0) : "v"(a0), "v"(a1));
      asm("v_cvt_pk_bf16_f32 %0, %1, %2" : "=v"(d1) : "v"(a2), "v"(a3));
      const uint mb = (uint)((16 * s + lg * 4) * 2);
      char* wp = Pw + pwr + (int)((mb & 15u) | ((mb & ~15u) ^ pswz));
      unsigned long long v = (unsigned long long)d0 | ((unsigned long long)d1 << 32);
      *(unsigned long long*)wp = v;
    }
#pragma unroll
    for (int k = 0; k < 2; ++k) {
      const uint rb = (uint)(lg * 16 + 64 * k);
      bf16x8 pbf = ld_bf8((const ushort_t*)(Pw + pwr + (int)(rb ^ pswz)));
#pragma unroll
      for (int s = 0; s < 4; ++s)
        acc[s] = __builtin_amdgcn_mfma_f32_16x16x32_bf16(ga[s][k], pbf, acc[s], 0, 0, 0);
    }
  }
  const float inv = 1.f / l_run;
  float* yB = y + ((size_t)b * NN + q0 + w * 16 + l15) * 64;
#pragma unroll
  for (int s = 0; s < 4; ++s) {
    float4 o;
    o.x = acc[s][0] * inv;
    o.y = acc[s][1] * inv;
    o.z = acc[s][2] * inv;
    o.w = acc[s][3] * inv;
    *(float4*)(yB + 16 * s + lg * 4) = o;
  }
}

// ---------------------------------------------------------------------------
// W_y stats via Gram matrix (unchanged).
// ---------------------------------------------------------------------------
__global__ void zero_kernel(float* __restrict__ p, int n) {
  int i = blockIdx.x * blockDim.x + threadIdx.x;
  if (i < n) p[i] = 0.f;
}

__global__ __launch_bounds__(256) void gram_kernel(const float* __restrict__ y,
                                                   float* __restrict__ Gm) {
  __shared__ float ys[64][65];
  const int b = blockIdx.y;
  const int m0 = blockIdx.x * 64;
  const int t = threadIdx.x;
  const float* yb = y + (size_t)b * (NN * C8);
#pragma unroll
  for (int j = 0; j < 16; ++j) {
    int k = (t >> 6) + j * 4;
    ys[k][t & 63] = yb[(size_t)k * NN + m0 + (t & 63)];
  }
  __syncthreads();
  const int k = t >> 2;
  const int k2b = (t & 3) * 16;
  float a_[16];
#pragma unroll
  for (int i = 0; i < 16; ++i) a_[i] = 0.f;
  for (int m = 0; m < 64; ++m) {
    float av = ys[k][m];
#pragma unroll
    for (int i = 0; i < 16; ++i) a_[i] += av * ys[k2b + i][m];
  }
#pragma unroll
  for (int i = 0; i < 16; ++i)
    atomicAdd(&Gm[(size_t)b * 4096 + k * 64 + k2b + i], a_[i]);
}

__global__ __launch_bounds__(64) void ybar_kernel(const float* __restrict__ y,
                                                  float* __restrict__ yb) {
  const int k = blockIdx.x, b = blockIdx.y, l = threadIdx.x;
  const float* row = y + (size_t)b * (NN * C8) + (size_t)k * NN;
  float s = 0.f;
  for (int j = l; j < NN; j += 64) s += row[j];
#pragma unroll
  for (int off = 32; off >= 1; off >>= 1) s += __shfl_xor(s, off);
  if (l == 0) yb[b * 64 + k] = s * (1.f / NN);
}

__global__ __launch_bounds__(64) void wy_stats_kernel(
    const float* __restrict__ Gm, const float* __restrict__ ybar,
    const float* __restrict__ Ww, const float* __restrict__ Wb,
    float* __restrict__ mu_s, float* __restrict__ std_s) {
  __shared__ float ww[64];
  const int o = blockIdx.x, b = blockIdx.y, l = threadIdx.x;
  ww[l] = Ww[o * 64 + l];
  __syncthreads();
  const float* Gb = Gm + (size_t)b * 4096;
  float colsum = 0.f;
  for (int k = 0; k < 64; ++k) colsum += ww[k] * Gb[k * 64 + l];
  float qq = ww[l] * colsum;
  float md = ww[l] * ybar[b * 64 + l];
#pragma unroll
  for (int off = 32; off >= 1; off >>= 1) {
    qq += __shfl_xor(qq, off);
    md += __shfl_xor(md, off);
  }
  if (l == 0) {
    float bias = Wb[o];
    float mu = md + bias;
    float ex2 = qq * (1.f / NN) + 2.f * bias * md + bias * bias;
    float var = ex2 - mu * mu;
    mu_s[b * CC + o] = mu;
    std_s[b * CC + o] = sqrtf(fmaxf(var, 0.f) + EPSI);
  }
}

// ---------------------------------------------------------------------------
// x0 instance stats + AdaIN epilogue (unchanged).
// ---------------------------------------------------------------------------
__global__ __launch_bounds__(256) void x_stats_kernel(const float* __restrict__ x0,
                                                      float* __restrict__ mu_c,
                                                      float* __restrict__ rstd_c) {
  __shared__ float redA[4], redB[4];
  const int c = blockIdx.x, b = blockIdx.y, t = threadIdx.x;
  const float4* xi = (const float4*)(x0 + ((size_t)b * CC + c) * NN);
  float s1 = 0.f, s2 = 0.f;
#pragma unroll
  for (int j = t; j < NN / 4; j += 256) {
    float4 v = xi[j];
    s1 += v.x + v.y + v.z + v.w;
    s2 += v.x * v.x + v.y * v.y + v.z * v.z + v.w * v.w;
  }
#pragma unroll
  for (int off = 32; off >= 1; off >>= 1) {
    s1 += __shfl_xor(s1, off);
    s2 += __shfl_xor(s2, off);
  }
  if ((t & 63) == 0) { redA[t >> 6] = s1; redB[t >> 6] = s2; }
  __syncthreads();
  if (t == 0) {
    float S1 = redA[0] + redA[1] + redA[2] + redA[3];
    float S2 = redB[0] + redB[1] + redB[2] + redB[3];
    float mean = S1 * (1.f / NN);
    float var = S2 * (1.f / NN) - mean * mean;
    mu_c[b * CC + c] = mean;
    rstd_c[b * CC + c] = 1.f / sqrtf(var + EPSI);
  }
}

__global__ __launch_bounds__(256) void adain_kernel(
    const float* __restrict__ x0, const float* __restrict__ mu_c,
    const float* __restrict__ rstd_c, const float* __restrict__ mu_s,
    const float* __restrict__ std_s, float* __restrict__ out) {
  const int c = blockIdx.x, b = blockIdx.y, t = threadIdx.x;
  const int bc = b * CC + c;
  const float scale = std_s[bc] * rstd_c[bc];
  const float shift = mu_s[bc] - scale * mu_c[bc];
  const float4* xi = (const float4*)(x0 + (size_t)bc * NN);
  float4* oo = (float4*)(out + (size_t)bc * NN);
#pragma unroll
  for (int j = t; j < NN / 4; j += 256) {
    float4 v = xi[j];
    v.x = v.x * scale + shift;
    v.y = v.y * scale + shift;
    v.z = v.z * scale + shift;
    v.w = v.w * scale + shift;
    oo[j] = v;
  }
}

extern "C" void kernel_launch(void* const* d_in, const int* in_sizes, int n_in,
                              void* d_out, int out_size, void* d_ws, size_t ws_size,
                              hipStream_t stream) {
  (void)in_sizes; (void)n_in; (void)out_size; (void)ws_size;
  const float* x0 = (const float*)d_in[0];
  const float* x1 = (const float*)d_in[1];
  const float* g_w = (const float*)d_in[2];
  const float* g_b = (const float*)d_in[3];
  const float* theta_w = (const float*)d_in[4];
  const float* theta_b = (const float*)d_in[5];
  const float* phi_w = (const float*)d_in[6];
  const float* phi_b = (const float*)d_in[7];
  const float* W_w = (const float*)d_in[8];
  const float* W_b = (const float*)d_in[9];
  float* out = (float*)d_out;
  float* ws = (float*)d_ws;

  ushort_t* thetaT = (ushort_t*)ws;              // [B][N][64] bf16
  ushort_t* phiT = (ushort_t*)(ws + 524288);     // [B][N][64] bf16
  ushort_t* gbf = (ushort_t*)(ws + 1048576);     // [B][64][N] bf16
  float* y = ws + 1572864;                       // [B][N][64] f32
  float* Gm = ws + 2621440;                      // [B][64][64]
  float* yb = ws + 2637824;                      // [B][64]
  float* mu_s = ws + 2638080;                    // [B][C]
  float* std_s = ws + 2640128;
  float* mu_c = ws + 2642176;
  float* rstd_c = ws + 2644224;
  ushort_t* twb = (ushort_t*)(ws + 2646272);     // [64][512] bf16
  ushort_t* pwb = (ushort_t*)(ws + 2662656);
  ushort_t* gwb = (ushort_t*)(ws + 2679040);

  wconv_kernel<<<dim3(96), 256, 0, stream>>>(theta_w, phi_w, g_w, twb, pwb, gwb);
  proj2_mfma_kernel<<<dim3(128, BB), 256, 0, stream>>>(x1, twb, theta_b, pwb,
                                                       phi_b, thetaT, phiT);
  proj1_mfma_kernel<<<dim3(128, BB), 256, 0, stream>>>(x0, gwb, g_b, gbf);
  attn_mfma_kernel<<<dim3(128, BB), 128, 0, stream>>>(thetaT, phiT, gbf, y);
  zero_kernel<<<dim3(64), 256, 0, stream>>>(Gm, BB * 64 * 64);
  gram_kernel<<<dim3(64, BB), 256, 0, stream>>>(y, Gm);
  ybar_kernel<<<dim3(64, BB), 64, 0, stream>>>(y, yb);
  wy_stats_kernel<<<dim3(CC, BB), 64, 0, stream>>>(Gm, yb, W_w, W_b, mu_s, std_s);
  x_stats_kernel<<<dim3(CC, BB), 256, 0, stream>>>(x0, mu_c, rstd_c);
  adain_kernel<<<dim3(CC, BB), 256, 0, stream>>>(x0, mu_c, rstd_c, mu_s, std_s, out);
}

// Round 9
// 302.587 us; speedup vs baseline: 2.7968x; 1.1751x over previous
//
#include <hip/hip_runtime.h>

#define BB 4
#define CC 512
#define C8 64
#define NN 4096
#define EPSI 1e-5f

typedef unsigned short ushort_t;
typedef unsigned int uint;
typedef __bf16 bf16x8 __attribute__((ext_vector_type(8)));
typedef float f32x4 __attribute__((ext_vector_type(4)));

__device__ inline ushort_t f2bf(float f) {
  uint u = __float_as_uint(f);
  uint r = (u + 0x7FFFu + ((u >> 16) & 1u)) >> 16;  // RNE
  return (ushort_t)r;
}

__device__ inline bf16x8 ld_bf8(const ushort_t* p) {
  uint4 u = *(const uint4*)p;
  return __builtin_bit_cast(bf16x8, u);
}

// ---------------------------------------------------------------------------
// Weight fp32 -> bf16 convert (layout [r][512], k-contiguous: A-frag ready).
// ---------------------------------------------------------------------------
__global__ __launch_bounds__(256) void wconv_kernel(
    const float* __restrict__ tw, const float* __restrict__ pw,
    const float* __restrict__ gw, ushort_t* __restrict__ twb,
    ushort_t* __restrict__ pwb, ushort_t* __restrict__ gwb) {
  const int sec = blockIdx.x >> 5;
  const int idx = ((blockIdx.x & 31) * 256 + threadIdx.x) * 4;
  const float* src = sec == 0 ? tw : (sec == 1 ? pw : gw);
  ushort_t* dst = sec == 0 ? twb : (sec == 1 ? pwb : gwb);
  float4 v = *(const float4*)(src + idx);
  uint2 pk;
  pk.x = (uint)f2bf(v.x) | ((uint)f2bf(v.y) << 16);
  pk.y = (uint)f2bf(v.z) | ((uint)f2bf(v.w) << 16);
  *(uint2*)(dst + idx) = pk;
}

// ---------------------------------------------------------------------------
// MFMA projection of x1 -> thetaT, phiT  [B][N][64] bf16 (unchanged, r8-pass).
// ---------------------------------------------------------------------------
__global__ __launch_bounds__(256) void proj2_mfma_kernel(
    const float* __restrict__ x1,
    const ushort_t* __restrict__ twb, const float* __restrict__ tb,
    const ushort_t* __restrict__ pwb, const float* __restrict__ pb,
    ushort_t* __restrict__ thetaT, ushort_t* __restrict__ phiT) {
  __shared__ char xT[32 * 128];   // [32 n][64 k] bf16, 16B-chunk XOR swizzle
  const int b = blockIdx.y;
  const int n0 = blockIdx.x * 32;
  const int t = threadIdx.x;
  const int l = t & 63;
  const int w = t >> 6;
  const int l15 = l & 15;
  const int lg = l >> 4;
  const int ns = w & 1;
  const int isphi = w >> 1;
  const float* xb = x1 + (size_t)b * CC * NN;
  const ushort_t* wb = isphi ? pwb : twb;
  const float* bias = isphi ? pb : tb;
  ushort_t* outp = isphi ? phiT : thetaT;

  f32x4 acc[4];
#pragma unroll
  for (int s = 0; s < 4; ++s) acc[s] = {0.f, 0.f, 0.f, 0.f};

  const int ldrow = t >> 3;   // 0..31
  const int ldc4 = t & 7;
  const int nfr = ns * 16 + l15;
  const int fchunkbase = nfr * 128;
  for (int k0 = 0; k0 < CC; k0 += 64) {
    __syncthreads();
#pragma unroll
    for (int p = 0; p < 2; ++p) {
      const int kr = ldrow + p * 32;
      float4 v = *(const float4*)(xb + (size_t)(k0 + kr) * NN + n0 + ldc4 * 4);
      ushort_t e0 = f2bf(v.x), e1 = f2bf(v.y), e2 = f2bf(v.z), e3 = f2bf(v.w);
      const int chunk = kr >> 3;
      const int kin = (kr & 7) * 2;
#pragma unroll
      for (int j = 0; j < 4; ++j) {
        const int n = ldc4 * 4 + j;
        ushort_t e = j == 0 ? e0 : (j == 1 ? e1 : (j == 2 ? e2 : e3));
        *(ushort_t*)(xT + n * 128 + (((chunk ^ (n & 7)) << 4) | kin)) = e;
      }
    }
    __syncthreads();
#pragma unroll
    for (int ks = 0; ks < 2; ++ks) {
      bf16x8 bx = *(const bf16x8*)(xT + fchunkbase +
                                   (((ks * 4 + lg) ^ (nfr & 7)) << 4));
#pragma unroll
      for (int rs = 0; rs < 4; ++rs) {
        bf16x8 aw = ld_bf8(wb + (size_t)(rs * 16 + l15) * 512 + k0 + ks * 32 + lg * 8);
        acc[rs] = __builtin_amdgcn_mfma_f32_16x16x32_bf16(aw, bx, acc[rs], 0, 0, 0);
      }
    }
  }
  const size_t nrow = (size_t)b * NN + n0 + ns * 16 + l15;
#pragma unroll
  for (int rs = 0; rs < 4; ++rs) {
    float4 bv = *(const float4*)(bias + rs * 16 + lg * 4);
    float a0 = acc[rs][0] + bv.x;
    float a1 = acc[rs][1] + bv.y;
    float a2 = acc[rs][2] + bv.z;
    float a3 = acc[rs][3] + bv.w;
    uint d0, d1;
    asm("v_cvt_pk_bf16_f32 %0, %1, %2" : "=v"(d0) : "v"(a0), "v"(a1));
    asm("v_cvt_pk_bf16_f32 %0, %1, %2" : "=v"(d1) : "v"(a2), "v"(a3));
    uint2 pk; pk.x = d0; pk.y = d1;
    *(uint2*)(outp + nrow * 64 + rs * 16 + lg * 4) = pk;
  }
}

// ---------------------------------------------------------------------------
// MFMA projection of x0 -> g [B][64][N] bf16 (unchanged, r8-pass).
// ---------------------------------------------------------------------------
__global__ __launch_bounds__(256) void proj1_mfma_kernel(
    const float* __restrict__ x0,
    const ushort_t* __restrict__ gwb, const float* __restrict__ gbias,
    ushort_t* __restrict__ g) {
  __shared__ char xT[32 * 128];
  const int b = blockIdx.y;
  const int n0 = blockIdx.x * 32;
  const int t = threadIdx.x;
  const int l = t & 63;
  const int w = t >> 6;
  const int l15 = l & 15;
  const int lg = l >> 4;
  const int ns = w & 1;
  const int rh = w >> 1;
  const float* xb = x0 + (size_t)b * CC * NN;

  f32x4 acc[2];
#pragma unroll
  for (int s = 0; s < 2; ++s) acc[s] = {0.f, 0.f, 0.f, 0.f};

  const int ldrow = t >> 3;
  const int ldc4 = t & 7;
  const int nfr = ns * 16 + l15;
  const int fchunkbase = nfr * 128;
  for (int k0 = 0; k0 < CC; k0 += 64) {
    __syncthreads();
#pragma unroll
    for (int p = 0; p < 2; ++p) {
      const int kr = ldrow + p * 32;
      float4 v = *(const float4*)(xb + (size_t)(k0 + kr) * NN + n0 + ldc4 * 4);
      ushort_t e0 = f2bf(v.x), e1 = f2bf(v.y), e2 = f2bf(v.z), e3 = f2bf(v.w);
      const int chunk = kr >> 3;
      const int kin = (kr & 7) * 2;
#pragma unroll
      for (int j = 0; j < 4; ++j) {
        const int n = ldc4 * 4 + j;
        ushort_t e = j == 0 ? e0 : (j == 1 ? e1 : (j == 2 ? e2 : e3));
        *(ushort_t*)(xT + n * 128 + (((chunk ^ (n & 7)) << 4) | kin)) = e;
      }
    }
    __syncthreads();
#pragma unroll
    for (int ks = 0; ks < 2; ++ks) {
      bf16x8 bx = *(const bf16x8*)(xT + fchunkbase +
                                   (((ks * 4 + lg) ^ (nfr & 7)) << 4));
#pragma unroll
      for (int j = 0; j < 2; ++j) {
        const int rs = rh * 2 + j;
        bf16x8 aw = ld_bf8(gwb + (size_t)(rs * 16 + l15) * 512 + k0 + ks * 32 + lg * 8);
        acc[j] = __builtin_amdgcn_mfma_f32_16x16x32_bf16(aw, bx, acc[j], 0, 0, 0);
      }
    }
  }
  const int ncol = n0 + ns * 16 + l15;
#pragma unroll
  for (int j = 0; j < 2; ++j) {
    const int rbase = (rh * 2 + j) * 16 + lg * 4;
    float4 bv = *(const float4*)(gbias + rbase);
    g[((size_t)b * 64 + rbase + 0) * NN + ncol] = f2bf(acc[j][0] + bv.x);
    g[((size_t)b * 64 + rbase + 1) * NN + ncol] = f2bf(acc[j][1] + bv.y);
    g[((size_t)b * 64 + rbase + 2) * NN + ncol] = f2bf(acc[j][2] + bv.z);
    g[((size_t)b * 64 + rbase + 3) * NN + ncol] = f2bf(acc[j][3] + bv.w);
  }
}

// ---------------------------------------------------------------------------
// MFMA flash attention, 4-way in-block m-split (flash-decoding style).
// 256 threads = 4 waves; wave w owns m-quarter [w*1024, (w+1)*1024) for the
// SAME 32 q-rows (two 16-q groups sharing every theta/g A-frag -> halves L2
// traffic). Each wave keeps private online-softmax state; after the m-loop,
// partials (acc, m, l) merge exactly in LDS (one barrier).
// ---------------------------------------------------------------------------
__global__ __launch_bounds__(256) void attn_mfma_kernel(
    const ushort_t* __restrict__ thT,  // [B][N][64] bf16 (n-major)
    const ushort_t* __restrict__ phT,  // [B][N][64] bf16 (n-major)
    const ushort_t* __restrict__ gm,   // [B][64][N] bf16 (c-major)
    float* __restrict__ y) {           // [B][N][64] f32
  __shared__ char Plds[4][2][2048];    // [wave][qg] P^T tile, swizzled
  __shared__ float pacc[4][32][64];    // [wave][q][c] partial acc
  __shared__ float pm[4][32], pl[4][32];
  const int b = blockIdx.y;
  const int q0 = blockIdx.x * 32;
  const int tid = threadIdx.x;
  const int l = tid & 63;
  const int w = tid >> 6;          // m-quarter
  const int l15 = l & 15;
  const int lg = l >> 4;
  const ushort_t* thB = thT + (size_t)b * NN * 64;
  const ushort_t* phB = phT + (size_t)b * NN * 64;
  const ushort_t* gB = gm + (size_t)b * 64 * NN;

  // hoisted Q (phi) B-frags for both q-groups
  bf16x8 qf[2][2];
#pragma unroll
  for (int qg = 0; qg < 2; ++qg) {
    const ushort_t* p = phB + (size_t)(q0 + qg * 16 + l15) * 64 + lg * 8;
    qf[qg][0] = ld_bf8(p);
    qf[qg][1] = ld_bf8(p + 32);
  }

  float m_run[2] = {-1e30f, -1e30f}, l_run[2] = {0.f, 0.f};
  f32x4 acc[2][4];
#pragma unroll
  for (int qg = 0; qg < 2; ++qg)
#pragma unroll
    for (int s = 0; s < 4; ++s) acc[qg][s] = {0.f, 0.f, 0.f, 0.f};

  const ushort_t* thL = thB + (size_t)l15 * 64 + lg * 8;
  const ushort_t* gL = gB + (size_t)l15 * 4096 + lg * 8;
  const int pwr = l15 * 128;
  const uint pswz = (uint)((l & 7) << 4);
  const int mbeg = w * (NN / 4);

  for (int m0 = mbeg; m0 < mbeg + NN / 4; m0 += 64) {
    // ---- QK^T for both q-groups, sharing A-frags ----
    f32x4 st[2][4];
#pragma unroll
    for (int qg = 0; qg < 2; ++qg)
#pragma unroll
      for (int s = 0; s < 4; ++s) st[qg][s] = {0.f, 0.f, 0.f, 0.f};
#pragma unroll
    for (int s = 0; s < 4; ++s) {
      const ushort_t* ts = thL + (size_t)(m0 + 16 * s) * 64;
      bf16x8 a0 = ld_bf8(ts);
      bf16x8 a1 = ld_bf8(ts + 32);
      st[0][s] = __builtin_amdgcn_mfma_f32_16x16x32_bf16(a0, qf[0][0], st[0][s], 0, 0, 0);
      st[1][s] = __builtin_amdgcn_mfma_f32_16x16x32_bf16(a0, qf[1][0], st[1][s], 0, 0, 0);
      st[0][s] = __builtin_amdgcn_mfma_f32_16x16x32_bf16(a1, qf[0][1], st[0][s], 0, 0, 0);
      st[1][s] = __builtin_amdgcn_mfma_f32_16x16x32_bf16(a1, qf[1][1], st[1][s], 0, 0, 0);
    }
    // ---- g A-frags (shared by both q-groups), issued before softmax ----
    bf16x8 ga[4][2];
#pragma unroll
    for (int s = 0; s < 4; ++s) {
      const ushort_t* gs = gL + (size_t)s * 16 * 4096 + m0;
      ga[s][0] = ld_bf8(gs);
      ga[s][1] = ld_bf8(gs + 32);
    }
    // ---- online softmax + P-store per q-group ----
#pragma unroll
    for (int qg = 0; qg < 2; ++qg) {
      float tmax = -1e30f;
#pragma unroll
      for (int s = 0; s < 4; ++s)
#pragma unroll
        for (int r = 0; r < 4; ++r) tmax = fmaxf(tmax, st[qg][s][r]);
      tmax = fmaxf(tmax, __shfl_xor(tmax, 16));
      tmax = fmaxf(tmax, __shfl_xor(tmax, 32));
      const float mn = fmaxf(m_run[qg], tmax);
      const float sc = __expf(m_run[qg] - mn);
      float tsum = 0.f;
#pragma unroll
      for (int s = 0; s < 4; ++s)
#pragma unroll
        for (int r = 0; r < 4; ++r) {
          float p = __expf(st[qg][s][r] - mn);
          st[qg][s][r] = p;
          tsum += p;
        }
      tsum += __shfl_xor(tsum, 16);
      tsum += __shfl_xor(tsum, 32);
      l_run[qg] = l_run[qg] * sc + tsum;
      m_run[qg] = mn;
#pragma unroll
      for (int s = 0; s < 4; ++s) acc[qg][s] *= sc;
      char* Pw = Plds[w][qg];
#pragma unroll
      for (int s = 0; s < 4; ++s) {
        uint d0, d1;
        float a0 = st[qg][s][0], a1 = st[qg][s][1], a2 = st[qg][s][2], a3 = st[qg][s][3];
        asm("v_cvt_pk_bf16_f32 %0, %1, %2" : "=v"(d0) : "v"(a0), "v"(a1));
        asm("v_cvt_pk_bf16_f32 %0, %1, %2" : "=v"(d1) : "v"(a2), "v"(a3));
        const uint mb = (uint)((16 * s + lg * 4) * 2);
        char* wp = Pw + pwr + (int)((mb & 15u) | ((mb & ~15u) ^ pswz));
        unsigned long long v = (unsigned long long)d0 | ((unsigned long long)d1 << 32);
        *(unsigned long long*)wp = v;
      }
    }
    // ---- PV for both q-groups, sharing ga ----
#pragma unroll
    for (int qg = 0; qg < 2; ++qg) {
      char* Pw = Plds[w][qg];
#pragma unroll
      for (int k = 0; k < 2; ++k) {
        const uint rb = (uint)(lg * 16 + 64 * k);
        bf16x8 pbf = ld_bf8((const ushort_t*)(Pw + pwr + (int)(rb ^ pswz)));
#pragma unroll
        for (int s = 0; s < 4; ++s)
          acc[qg][s] = __builtin_amdgcn_mfma_f32_16x16x32_bf16(ga[s][k], pbf, acc[qg][s], 0, 0, 0);
      }
    }
  }
  // ---- write per-wave partials and merge ----
#pragma unroll
  for (int qg = 0; qg < 2; ++qg) {
    const int q = qg * 16 + l15;
#pragma unroll
    for (int s = 0; s < 4; ++s)
      *(f32x4*)&pacc[w][q][16 * s + lg * 4] = acc[qg][s];
    if (lg == 0) {
      pm[w][q] = m_run[qg];
      pl[w][q] = l_run[qg];
    }
  }
  __syncthreads();
  {
    const int q = tid >> 3;          // 0..31
    const int cb = (tid & 7) * 8;    // 0..56
    float m0v = pm[0][q], m1v = pm[1][q], m2v = pm[2][q], m3v = pm[3][q];
    float M = fmaxf(fmaxf(m0v, m1v), fmaxf(m2v, m3v));
    float e0 = __expf(m0v - M), e1 = __expf(m1v - M);
    float e2 = __expf(m2v - M), e3 = __expf(m3v - M);
    float L = pl[0][q] * e0 + pl[1][q] * e1 + pl[2][q] * e2 + pl[3][q] * e3;
    float inv = 1.f / L;
    float* yB = y + ((size_t)b * NN + q0 + q) * 64 + cb;
#pragma unroll
    for (int h = 0; h < 2; ++h) {
      float4 o;
      o.x = (pacc[0][q][cb + 4 * h + 0] * e0 + pacc[1][q][cb + 4 * h + 0] * e1 +
             pacc[2][q][cb + 4 * h + 0] * e2 + pacc[3][q][cb + 4 * h + 0] * e3) * inv;
      o.y = (pacc[0][q][cb + 4 * h + 1] * e0 + pacc[1][q][cb + 4 * h + 1] * e1 +
             pacc[2][q][cb + 4 * h + 1] * e2 + pacc[3][q][cb + 4 * h + 1] * e3) * inv;
      o.z = (pacc[0][q][cb + 4 * h + 2] * e0 + pacc[1][q][cb + 4 * h + 2] * e1 +
             pacc[2][q][cb + 4 * h + 2] * e2 + pacc[3][q][cb + 4 * h + 2] * e3) * inv;
      o.w = (pacc[0][q][cb + 4 * h + 3] * e0 + pacc[1][q][cb + 4 * h + 3] * e1 +
             pacc[2][q][cb + 4 * h + 3] * e2 + pacc[3][q][cb + 4 * h + 3] * e3) * inv;
      *(float4*)(yB + 4 * h) = o;
    }
  }
}

// ---------------------------------------------------------------------------
// W_y stats via Gram matrix (unchanged).
// ---------------------------------------------------------------------------
__global__ void zero_kernel(float* __restrict__ p, int n) {
  int i = blockIdx.x * blockDim.x + threadIdx.x;
  if (i < n) p[i] = 0.f;
}

__global__ __launch_bounds__(256) void gram_kernel(const float* __restrict__ y,
                                                   float* __restrict__ Gm) {
  __shared__ float ys[64][65];
  const int b = blockIdx.y;
  const int m0 = blockIdx.x * 64;
  const int t = threadIdx.x;
  const float* yb = y + (size_t)b * (NN * C8);
#pragma unroll
  for (int j = 0; j < 16; ++j) {
    int k = (t >> 6) + j * 4;
    ys[k][t & 63] = yb[(size_t)k * NN + m0 + (t & 63)];
  }
  __syncthreads();
  const int k = t >> 2;
  const int k2b = (t & 3) * 16;
  float a_[16];
#pragma unroll
  for (int i = 0; i < 16; ++i) a_[i] = 0.f;
  for (int m = 0; m < 64; ++m) {
    float av = ys[k][m];
#pragma unroll
    for (int i = 0; i < 16; ++i) a_[i] += av * ys[k2b + i][m];
  }
#pragma unroll
  for (int i = 0; i < 16; ++i)
    atomicAdd(&Gm[(size_t)b * 4096 + k * 64 + k2b + i], a_[i]);
}

__global__ __launch_bounds__(64) void ybar_kernel(const float* __restrict__ y,
                                                  float* __restrict__ yb) {
  const int k = blockIdx.x, b = blockIdx.y, l = threadIdx.x;
  const float* row = y + (size_t)b * (NN * C8) + (size_t)k * NN;
  float s = 0.f;
  for (int j = l; j < NN; j += 64) s += row[j];
#pragma unroll
  for (int off = 32; off >= 1; off >>= 1) s += __shfl_xor(s, off);
  if (l == 0) yb[b * 64 + k] = s * (1.f / NN);
}

__global__ __launch_bounds__(64) void wy_stats_kernel(
    const float* __restrict__ Gm, const float* __restrict__ ybar,
    const float* __restrict__ Ww, const float* __restrict__ Wb,
    float* __restrict__ mu_s, float* __restrict__ std_s) {
  __shared__ float ww[64];
  const int o = blockIdx.x, b = blockIdx.y, l = threadIdx.x;
  ww[l] = Ww[o * 64 + l];
  __syncthreads();
  const float* Gb = Gm + (size_t)b * 4096;
  float colsum = 0.f;
  for (int k = 0; k < 64; ++k) colsum += ww[k] * Gb[k * 64 + l];
  float qq = ww[l] * colsum;
  float md = ww[l] * ybar[b * 64 + l];
#pragma unroll
  for (int off = 32; off >= 1; off >>= 1) {
    qq += __shfl_xor(qq, off);
    md += __shfl_xor(md, off);
  }
  if (l == 0) {
    float bias = Wb[o];
    float mu = md + bias;
    float ex2 = qq * (1.f / NN) + 2.f * bias * md + bias * bias;
    float var = ex2 - mu * mu;
    mu_s[b * CC + o] = mu;
    std_s[b * CC + o] = sqrtf(fmaxf(var, 0.f) + EPSI);
  }
}

// ---------------------------------------------------------------------------
// x0 instance stats + AdaIN epilogue (unchanged).
// ---------------------------------------------------------------------------
__global__ __launch_bounds__(256) void x_stats_kernel(const float* __restrict__ x0,
                                                      float* __restrict__ mu_c,
                                                      float* __restrict__ rstd_c) {
  __shared__ float redA[4], redB[4];
  const int c = blockIdx.x, b = blockIdx.y, t = threadIdx.x;
  const float4* xi = (const float4*)(x0 + ((size_t)b * CC + c) * NN);
  float s1 = 0.f, s2 = 0.f;
#pragma unroll
  for (int j = t; j < NN / 4; j += 256) {
    float4 v = xi[j];
    s1 += v.x + v.y + v.z + v.w;
    s2 += v.x * v.x + v.y * v.y + v.z * v.z + v.w * v.w;
  }
#pragma unroll
  for (int off = 32; off >= 1; off >>= 1) {
    s1 += __shfl_xor(s1, off);
    s2 += __shfl_xor(s2, off);
  }
  if ((t & 63) == 0) { redA[t >> 6] = s1; redB[t >> 6] = s2; }
  __syncthreads();
  if (t == 0) {
    float S1 = redA[0] + redA[1] + redA[2] + redA[3];
    float S2 = redB[0] + redB[1] + redB[2] + redB[3];
    float mean = S1 * (1.f / NN);
    float var = S2 * (1.f / NN) - mean * mean;
    mu_c[b * CC + c] = mean;
    rstd_c[b * CC + c] = 1.f / sqrtf(var + EPSI);
  }
}

__global__ __launch_bounds__(256) void adain_kernel(
    const float* __restrict__ x0, const float* __restrict__ mu_c,
    const float* __restrict__ rstd_c, const float* __restrict__ mu_s,
    const float* __restrict__ std_s, float* __restrict__ out) {
  const int c = blockIdx.x, b = blockIdx.y, t = threadIdx.x;
  const int bc = b * CC + c;
  const float scale = std_s[bc] * rstd_c[bc];
  const float shift = mu_s[bc] - scale * mu_c[bc];
  const float4* xi = (const float4*)(x0 + (size_t)bc * NN);
  float4* oo = (float4*)(out + (size_t)bc * NN);
#pragma unroll
  for (int j = t; j < NN / 4; j += 256) {
    float4 v = xi[j];
    v.x = v.x * scale + shift;
    v.y = v.y * scale + shift;
    v.z = v.z * scale + shift;
    v.w = v.w * scale + shift;
    oo[j] = v;
  }
}

extern "C" void kernel_launch(void* const* d_in, const int* in_sizes, int n_in,
                              void* d_out, int out_size, void* d_ws, size_t ws_size,
                              hipStream_t stream) {
  (void)in_sizes; (void)n_in; (void)out_size; (void)ws_size;
  const float* x0 = (const float*)d_in[0];
  const float* x1 = (const float*)d_in[1];
  const float* g_w = (const float*)d_in[2];
  const float* g_b = (const float*)d_in[3];
  const float* theta_w = (const float*)d_in[4];
  const float* theta_b = (const float*)d_in[5];
  const float* phi_w = (const float*)d_in[6];
  const float* phi_b = (const float*)d_in[7];
  const float* W_w = (const float*)d_in[8];
  const float* W_b = (const float*)d_in[9];
  float* out = (float*)d_out;
  float* ws = (float*)d_ws;

  ushort_t* thetaT = (ushort_t*)ws;              // [B][N][64] bf16
  ushort_t* phiT = (ushort_t*)(ws + 524288);     // [B][N][64] bf16
  ushort_t* gbf = (ushort_t*)(ws + 1048576);     // [B][64][N] bf16
  float* y = ws + 1572864;                       // [B][N][64] f32
  float* Gm = ws + 2621440;                      // [B][64][64]
  float* yb = ws + 2637824;                      // [B][64]
  float* mu_s = ws + 2638080;                    // [B][C]
  float* std_s = ws + 2640128;
  float* mu_c = ws + 2642176;
  float* rstd_c = ws + 2644224;
  ushort_t* twb = (ushort_t*)(ws + 2646272);     // [64][512] bf16
  ushort_t* pwb = (ushort_t*)(ws + 2662656);
  ushort_t* gwb = (ushort_t*)(ws + 2679040);

  wconv_kernel<<<dim3(96), 256, 0, stream>>>(theta_w, phi_w, g_w, twb, pwb, gwb);
  proj2_mfma_kernel<<<dim3(128, BB), 256, 0, stream>>>(x1, twb, theta_b, pwb,
                                                       phi_b, thetaT, phiT);
  proj1_mfma_kernel<<<dim3(128, BB), 256, 0, stream>>>(x0, gwb, g_b, gbf);
  attn_mfma_kernel<<<dim3(128, BB), 256, 0, stream>>>(thetaT, phiT, gbf, y);
  zero_kernel<<<dim3(64), 256, 0, stream>>>(Gm, BB * 64 * 64);
  gram_kernel<<<dim3(64, BB), 256, 0, stream>>>(y, Gm);
  ybar_kernel<<<dim3(64, BB), 64, 0, stream>>>(y, yb);
  wy_stats_kernel<<<dim3(CC, BB), 64, 0, stream>>>(Gm, yb, W_w, W_b, mu_s, std_s);
  x_stats_kernel<<<dim3(CC, BB), 256, 0, stream>>>(x0, mu_c, rstd_c);
  adain_kernel<<<dim3(CC, BB), 256, 0, stream>>>(x0, mu_c, rstd_c, mu_s, std_s, out);
}